// Round 4
// baseline (57003.406 us; speedup 1.0000x reference)
//
#include <hip/hip_runtime.h>
#include <hip/hip_cooperative_groups.h>

namespace cg = cooperative_groups;

#define NN 2048
#define NB 32
#define NT 500
#define WGS 512
#define NWG 256

// Decomposition (identical arithmetic to R3, which passed):
//  WG wg owns rows i0 = wg*8 .. i0+7, ALL 32 batches.
//  Compute thread t: rh4 = (t>>8)*4 (row half), jh = (t>>5)&7 (j-chunk of 256),
//                    b = t&31 (batch). 4 rows share each bit expansion.
//  Per (i,b) dot: 8 chunk partials (256 consecutive j, sequential fma over
//  x,y,z,w of each float4), combined strictly in chunk order by one thread.
// New in R4:
//  - custom two-level grid barrier (16 groups x 16 WGs) instead of cg::grid.sync
//    in the hot loop (one cg sync remains for ws init).
//  - register-double-buffered W prefetch (4-iteration blocks, fully unrolled,
//    static indices only).

__device__ __forceinline__ void grid_bar(unsigned int* bar, int wg, int t,
                                         unsigned int target) {
    __syncthreads();
    if (t == 0) {
        __threadfence();  // release: make bit publishes visible device-wide
        unsigned int* grp  = bar + (wg >> 4) * 64;  // 16 counters, 256B apart
        unsigned int* root = bar + 1024;
        unsigned int* gen  = bar + 1088;
        unsigned int a = __hip_atomic_fetch_add(grp, 1u, __ATOMIC_ACQ_REL,
                                                __HIP_MEMORY_SCOPE_AGENT);
        if (a == 15u) {
            __hip_atomic_store(grp, 0u, __ATOMIC_RELAXED, __HIP_MEMORY_SCOPE_AGENT);
            unsigned int r = __hip_atomic_fetch_add(root, 1u, __ATOMIC_ACQ_REL,
                                                    __HIP_MEMORY_SCOPE_AGENT);
            if (r == 15u) {
                __hip_atomic_store(root, 0u, __ATOMIC_RELAXED, __HIP_MEMORY_SCOPE_AGENT);
                __hip_atomic_fetch_add(gen, 1u, __ATOMIC_RELEASE,
                                       __HIP_MEMORY_SCOPE_AGENT);
            }
        }
        while (__hip_atomic_load(gen, __ATOMIC_RELAXED, __HIP_MEMORY_SCOPE_AGENT) < target)
            __builtin_amdgcn_s_sleep(1);
        __threadfence();  // acquire: invalidate caches for fresh bit reads
    }
    __syncthreads();
}

__launch_bounds__(WGS)
__global__ void reservoir_kernel(const float* __restrict__ x,
                                 const float* __restrict__ W,
                                 const float* __restrict__ bias,
                                 float* __restrict__ out,
                                 float* __restrict__ ws)
{
    cg::grid_group grid = cg::this_grid();

    __shared__ unsigned int lbits[NN];      // 8 KB spike bits (all 32 batches)
    __shared__ float lpart[8][8][32];       // 8 KB [jh][i_local][b]
    __shared__ float lout[2][NB][9];        // padded output stage
    __shared__ int   lcnt[8];

    unsigned int* bitsG  = (unsigned int*)ws;                       // [2][2048]
    int*          wgpart = (int*)((char*)ws + 2 * NN * 4);          // [NWG]
    unsigned int* bar    = (unsigned int*)((char*)ws + 20480);      // barrier state

    const int wg = blockIdx.x;
    const int t  = threadIdx.x;
    const int i0 = wg * 8;

    // zero spike-bit buffers + barrier state (deterministic per launch)
    { int g = wg * WGS + t;
      if (g < 2 * NN) bitsG[g] = 0u;
      if (g < 1152)   bar[g]   = 0u; }

    // compute-thread identity
    const int rh4 = (t >> 8) * 4;      // 0 or 4
    const int jh  = (t >> 5) & 7;      // chunk 0..7
    const int b   = t & 31;            // batch 0..31

    const float4* __restrict__ wr0 = (const float4*)(W + (size_t)(i0 + rh4 + 0) * NN) + jh * 64;
    const float4* __restrict__ wr1 = (const float4*)(W + (size_t)(i0 + rh4 + 1) * NN) + jh * 64;
    const float4* __restrict__ wr2 = (const float4*)(W + (size_t)(i0 + rh4 + 2) * NN) + jh * 64;
    const float4* __restrict__ wr3 = (const float4*)(W + (size_t)(i0 + rh4 + 3) * NN) + jh * 64;

    // combine-thread identity (t < 256): (row cil, batch cb)
    const int cil = t >> 5;
    const int cb  = t & 31;
    float mem = 0.0f, sp = 0.0f;
    float biasv = 0.0f;
    const float* xb = x;
    if (t < 256) { biasv = bias[i0 + cil]; xb = x + (size_t)cb * NT; }
    int cnt = 0;

    float* spk_rec = out + 1;
    float* mem_rec = out + 1 + (size_t)NT * NB * NN;

    grid.sync();   // init fence (once per launch)

    unsigned int bgen = 0;

    for (int step = 0; step < NT; ++step) {
        const int cur = step & 1;

        // stage spike bits (8 KB) to LDS, coalesced
        ((uint4*)lbits)[t] = ((const uint4*)(bitsG + (size_t)cur * NN))[t];
        float xv = xb[step];   // hoisted; in flight during FMA loop
        __syncthreads();

        // chunk partials: 4 rows x 1 batch over 256 consecutive j (sequential
        // order, identical to R3). Register-double-buffered W prefetch.
        float c0 = 0.0f, c1 = 0.0f, c2 = 0.0f, c3 = 0.0f;
        const uint4* bp = ((const uint4*)lbits) + jh * 64;
        {
            float4 wv[2][4][4];   // [buf][slot][row] -- all indices static
            #pragma unroll
            for (int s2 = 0; s2 < 4; ++s2) {
                wv[0][s2][0] = wr0[s2]; wv[0][s2][1] = wr1[s2];
                wv[0][s2][2] = wr2[s2]; wv[0][s2][3] = wr3[s2];
            }
            #pragma unroll
            for (int blk = 0; blk < 16; ++blk) {
                const int cbuf = blk & 1, nbuf = cbuf ^ 1;
                if (blk < 15) {
                    #pragma unroll
                    for (int s2 = 0; s2 < 4; ++s2) {
                        const int j4 = (blk + 1) * 4 + s2;
                        wv[nbuf][s2][0] = wr0[j4]; wv[nbuf][s2][1] = wr1[j4];
                        wv[nbuf][s2][2] = wr2[j4]; wv[nbuf][s2][3] = wr3[j4];
                    }
                }
                #pragma unroll
                for (int s2 = 0; s2 < 4; ++s2) {
                    const int jj = blk * 4 + s2;
                    const uint4  bu = bp[jj];
                    const float4 w0 = wv[cbuf][s2][0];
                    const float4 w1 = wv[cbuf][s2][1];
                    const float4 w2 = wv[cbuf][s2][2];
                    const float4 w3 = wv[cbuf][s2][3];
                    float s;
                    s = (float)((bu.x >> b) & 1u);
                    c0 = fmaf(w0.x, s, c0); c1 = fmaf(w1.x, s, c1);
                    c2 = fmaf(w2.x, s, c2); c3 = fmaf(w3.x, s, c3);
                    s = (float)((bu.y >> b) & 1u);
                    c0 = fmaf(w0.y, s, c0); c1 = fmaf(w1.y, s, c1);
                    c2 = fmaf(w2.y, s, c2); c3 = fmaf(w3.y, s, c3);
                    s = (float)((bu.z >> b) & 1u);
                    c0 = fmaf(w0.z, s, c0); c1 = fmaf(w1.z, s, c1);
                    c2 = fmaf(w2.z, s, c2); c3 = fmaf(w3.z, s, c3);
                    s = (float)((bu.w >> b) & 1u);
                    c0 = fmaf(w0.w, s, c0); c1 = fmaf(w1.w, s, c1);
                    c2 = fmaf(w2.w, s, c2); c3 = fmaf(w3.w, s, c3);
                }
            }
        }
        lpart[jh][rh4 + 0][b] = c0;
        lpart[jh][rh4 + 1][b] = c1;
        lpart[jh][rh4 + 2][b] = c2;
        lpart[jh][rh4 + 3][b] = c3;
        __syncthreads();

        if (t < 256) {
            // sequential combine over chunks (== R3 order, bit-exact)
            float d = lpart[0][cil][cb];
            #pragma unroll
            for (int k = 1; k < 8; ++k) d += lpart[k][cil][cb];

            float base = 0.95f * mem + xv + d + biasv;
            float nm   = base * (1.0f - sp);
            float ns   = (nm > 1.0f) ? 1.0f : 0.0f;
            mem = nm; sp = ns;
            cnt += (int)ns;

            // publish spike bits for next step
            unsigned long long bal = __ballot(ns > 0.5f);
            unsigned int* bw = bitsG + (size_t)(1 - cur) * NN;
            const int l  = t & 63;
            const int w2 = t >> 6;
            if (l == 0)  bw[i0 + 2 * w2]     = (unsigned int)(bal & 0xFFFFFFFFull);
            if (l == 32) bw[i0 + 2 * w2 + 1] = (unsigned int)(bal >> 32);

            lout[0][cb][cil] = ns;
            lout[1][cb][cil] = nm;
        }
        __syncthreads();

        // coalesced-ish output stores (8 consecutive floats per (step,b))
        {
            const int arr = t >> 8;
            const int r2  = t & 255;
            const int bb  = r2 >> 3;
            const int il  = r2 & 7;
            size_t o = ((size_t)step * NB + bb) * (size_t)NN + i0 + il;
            if (arr == 0) __builtin_nontemporal_store(lout[0][bb][il], &spk_rec[o]);
            else          __builtin_nontemporal_store(lout[1][bb][il], &mem_rec[o]);
        }

        grid_bar(bar, wg, t, ++bgen);
    }

    // average firing rate
    #pragma unroll
    for (int d2 = 1; d2 < 64; d2 <<= 1) cnt += __shfl_xor(cnt, d2, 64);
    if ((t & 63) == 0) lcnt[t >> 6] = cnt;
    __syncthreads();
    if (t == 0) {
        int s = 0;
        #pragma unroll
        for (int k = 0; k < 8; ++k) s += lcnt[k];
        wgpart[wg] = s;
    }
    grid_bar(bar, wg, t, ++bgen);
    if (wg == 0) {
        int ps = (t < NWG) ? wgpart[t] : 0;
        #pragma unroll
        for (int d2 = 1; d2 < 64; d2 <<= 1) ps += __shfl_xor(ps, d2, 64);
        if ((t & 63) == 0) lcnt[t >> 6] = ps;
        __syncthreads();
        if (t == 0) {
            long long s2 = 0;
            #pragma unroll
            for (int k = 0; k < 8; ++k) s2 += lcnt[k];
            out[0] = (float)((double)s2 / (double)((long long)NT * NB * NN));
        }
    }
}

extern "C" void kernel_launch(void* const* d_in, const int* in_sizes, int n_in,
                              void* d_out, int out_size, void* d_ws, size_t ws_size,
                              hipStream_t stream) {
    const float* x    = (const float*)d_in[0];  // (32, 500, 1)
    const float* W    = (const float*)d_in[1];  // (2048, 2048)
    const float* bias = (const float*)d_in[2];  // (2048,)
    float* out = (float*)d_out;
    float* ws  = (float*)d_ws;

    void* args[] = { (void*)&x, (void*)&W, (void*)&bias, (void*)&out, (void*)&ws };
    hipLaunchCooperativeKernel((const void*)reservoir_kernel,
                               dim3(NWG), dim3(WGS), args, 0, stream);
}

// Round 5
// 9977.081 us; speedup vs baseline: 5.7134x; 5.7134x over previous
//
#include <hip/hip_runtime.h>

#define NN 2048
#define NB 32
#define NT 500
#define WGS 512
#define NWG 256

// One kernel launch per time step (500 sequential dispatches in the stream /
// graph). Stream ordering between dispatches gives cross-XCD coherence --
// no grid.sync, no agent-scope fence storms (R4's 105 GB refetch lesson).
//
// Per-step decomposition == R3 (passed twice, bit-identical arithmetic):
//  WG wg owns rows i0 = wg*8 .. i0+7, ALL 32 batches.
//  Compute thread t: rh4 = (t>>8)*4, jh = (t>>5)&7 (j-chunk of 256), b = t&31.
//  Per (i,b) dot: 8 chunk partials (256 consecutive j, sequential fma over
//  x,y,z,w of each float4), combined strictly in chunk order by one thread.
//  Spikes bit-packed uint32 per j (32 batches), double-buffered in ws.

__global__ void init_kernel(unsigned int* __restrict__ bitsG, int* __restrict__ spkcnt) {
    int g = blockIdx.x * blockDim.x + threadIdx.x;
    if (g < NN) bitsG[g] = 0u;   // step-0 read buffer
    if (g == 0) *spkcnt = 0;
}

__launch_bounds__(WGS)
__global__ void step_kernel(const float* __restrict__ x,
                            const float* __restrict__ W,
                            const float* __restrict__ bias,
                            float* __restrict__ out,
                            unsigned int* __restrict__ bitsG,
                            int* __restrict__ spkcnt,
                            int step)
{
    __shared__ unsigned int lbits[NN];      // 8 KB spike bits (all 32 batches)
    __shared__ float lpart[8][8][32];       // 8 KB [jh][i_local][b]
    __shared__ float lout[2][NB][9];        // padded output stage
    __shared__ int   lcnt[4];

    const int wg = blockIdx.x;
    const int t  = threadIdx.x;
    const int i0 = wg * 8;
    const int cur = step & 1;

    // stage spike bits (8 KB) to LDS, coalesced
    ((uint4*)lbits)[t] = ((const uint4*)(bitsG + (size_t)cur * NN))[t];

    // compute-thread identity
    const int rh4 = (t >> 8) * 4;      // 0 or 4
    const int jh  = (t >> 5) & 7;      // chunk 0..7
    const int b   = t & 31;            // batch 0..31

    const float4* __restrict__ wr0 = (const float4*)(W + (size_t)(i0 + rh4 + 0) * NN) + jh * 64;
    const float4* __restrict__ wr1 = (const float4*)(W + (size_t)(i0 + rh4 + 1) * NN) + jh * 64;
    const float4* __restrict__ wr2 = (const float4*)(W + (size_t)(i0 + rh4 + 2) * NN) + jh * 64;
    const float4* __restrict__ wr3 = (const float4*)(W + (size_t)(i0 + rh4 + 3) * NN) + jh * 64;

    __syncthreads();

    // chunk partials: 4 rows x 1 batch over 256 consecutive j (sequential order)
    float c0 = 0.0f, c1 = 0.0f, c2 = 0.0f, c3 = 0.0f;
    const uint4* bp = ((const uint4*)lbits) + jh * 64;
    #pragma unroll 2
    for (int jj = 0; jj < 64; ++jj) {
        const float4 w0 = wr0[jj];
        const float4 w1 = wr1[jj];
        const float4 w2 = wr2[jj];
        const float4 w3 = wr3[jj];
        const uint4  bu = bp[jj];
        float s;
        s = (float)((bu.x >> b) & 1u);
        c0 = fmaf(w0.x, s, c0); c1 = fmaf(w1.x, s, c1);
        c2 = fmaf(w2.x, s, c2); c3 = fmaf(w3.x, s, c3);
        s = (float)((bu.y >> b) & 1u);
        c0 = fmaf(w0.y, s, c0); c1 = fmaf(w1.y, s, c1);
        c2 = fmaf(w2.y, s, c2); c3 = fmaf(w3.y, s, c3);
        s = (float)((bu.z >> b) & 1u);
        c0 = fmaf(w0.z, s, c0); c1 = fmaf(w1.z, s, c1);
        c2 = fmaf(w2.z, s, c2); c3 = fmaf(w3.z, s, c3);
        s = (float)((bu.w >> b) & 1u);
        c0 = fmaf(w0.w, s, c0); c1 = fmaf(w1.w, s, c1);
        c2 = fmaf(w2.w, s, c2); c3 = fmaf(w3.w, s, c3);
    }
    lpart[jh][rh4 + 0][b] = c0;
    lpart[jh][rh4 + 1][b] = c1;
    lpart[jh][rh4 + 2][b] = c2;
    lpart[jh][rh4 + 3][b] = c3;
    __syncthreads();

    if (t < 256) {
        const int cil = t >> 5;        // row 0..7
        const int cb  = t & 31;        // batch

        // sequential combine over chunks (== R3 order, bit-exact)
        float d = lpart[0][cil][cb];
        #pragma unroll
        for (int k = 1; k < 8; ++k) d += lpart[k][cil][cb];

        // previous state from records (step>0) or zeros (step==0)
        float mem = 0.0f, sp = 0.0f;
        if (step > 0) {
            size_t po = ((size_t)(step - 1) * NB + cb) * (size_t)NN + i0 + cil;
            mem = out[1 + (size_t)NT * NB * NN + po];   // mem_rec[step-1]
            sp  = out[1 + po];                          // spk_rec[step-1]
        }

        float xv   = x[(size_t)cb * NT + step];
        float base = 0.95f * mem + xv + d + bias[i0 + cil];
        float nm   = base * (1.0f - sp);
        float ns   = (nm > 1.0f) ? 1.0f : 0.0f;

        // publish spike bits for next step
        unsigned long long bal = __ballot(ns > 0.5f);
        unsigned int* bw = bitsG + (size_t)(1 - cur) * NN;
        const int l  = t & 63;
        const int w2 = t >> 6;
        if (l == 0)  bw[i0 + 2 * w2]     = (unsigned int)(bal & 0xFFFFFFFFull);
        if (l == 32) bw[i0 + 2 * w2 + 1] = (unsigned int)(bal >> 32);
        if (l == 0)  lcnt[w2] = __popcll(bal);

        lout[0][cb][cil] = ns;
        lout[1][cb][cil] = nm;
    }
    __syncthreads();

    if (t == 0) {
        int s = lcnt[0] + lcnt[1] + lcnt[2] + lcnt[3];
        if (s) atomicAdd(spkcnt, s);
    }

    // coalesced-ish output stores (8 consecutive floats per (step,b))
    {
        float* spk_rec = out + 1;
        float* mem_rec = out + 1 + (size_t)NT * NB * NN;
        const int arr = t >> 8;
        const int r2  = t & 255;
        const int bb  = r2 >> 3;
        const int il  = r2 & 7;
        size_t o = ((size_t)step * NB + bb) * (size_t)NN + i0 + il;
        if (arr == 0) spk_rec[o] = lout[0][bb][il];
        else          mem_rec[o] = lout[1][bb][il];
    }
}

__global__ void final_kernel(float* __restrict__ out, const int* __restrict__ spkcnt) {
    out[0] = (float)((double)(*spkcnt) / (double)((long long)NT * NB * NN));
}

extern "C" void kernel_launch(void* const* d_in, const int* in_sizes, int n_in,
                              void* d_out, int out_size, void* d_ws, size_t ws_size,
                              hipStream_t stream) {
    const float* x    = (const float*)d_in[0];  // (32, 500, 1)
    const float* W    = (const float*)d_in[1];  // (2048, 2048)
    const float* bias = (const float*)d_in[2];  // (2048,)
    float* out = (float*)d_out;

    unsigned int* bitsG  = (unsigned int*)d_ws;                 // [2][2048]
    int*          spkcnt = (int*)((char*)d_ws + 2 * NN * 4);

    init_kernel<<<dim3(8), dim3(256), 0, stream>>>(bitsG, spkcnt);
    for (int step = 0; step < NT; ++step) {
        step_kernel<<<dim3(NWG), dim3(WGS), 0, stream>>>(x, W, bias, out,
                                                         bitsG, spkcnt, step);
    }
    final_kernel<<<dim3(1), dim3(1), 0, stream>>>(out, spkcnt);
}

// Round 6
// 9404.185 us; speedup vs baseline: 6.0615x; 1.0609x over previous
//
#include <hip/hip_runtime.h>

#define NN 2048
#define NB 32
#define NT 500
#define WGS 1024
#define NWG 256

// One dispatch per time step (R5 structure, validated). R6: occupancy 2x
// (2 rows/thread, 262144 threads, 16 waves/CU), mem state in ws ([i][b]
// coalesced), spike state recomputed from bits, x pre-transposed, no atomics.
//
// Bit-exact summation order (R1/R3/R5-validated):
//  per (i,b): 8 chunk partials, chunk = 256 consecutive j accumulated
//  sequentially (x,y,z,w of each float4 in order), chunks combined 0..7
//  in order by the single (i,b) owner thread.
//
// ws layout: bitsG [2][2048] u32 @0 (16 KB) | mem_ws [2048][32] f32 @16384
//            (256 KB) | xT [500][32] f32 @278528 (64 KB) | wgcnt [256] @344064

__global__ void init_kernel(const float* __restrict__ x,
                            unsigned int* __restrict__ bitsG,
                            float* __restrict__ mem_ws,
                            float* __restrict__ xT,
                            int* __restrict__ wgcnt) {
    int g = blockIdx.x * blockDim.x + threadIdx.x;   // 65536 threads
    if (g < 2 * NN) bitsG[g] = 0u;
    if (g < NN * NB) mem_ws[g] = 0.0f;
    if (g < NT * NB) xT[g] = x[(size_t)(g & 31) * NT + (g >> 5)];
    if (g < NWG) wgcnt[g] = 0;
}

__launch_bounds__(WGS, 4)
__global__ void step_kernel(const float* __restrict__ W,
                            const float* __restrict__ bias,
                            float* __restrict__ out,
                            unsigned int* __restrict__ bitsG,
                            float* __restrict__ mem_ws,
                            const float* __restrict__ xT,
                            int* __restrict__ wgcnt,
                            int step)
{
    __shared__ unsigned int lbits[NN];      // 8 KB: all 2048 spike bits
    __shared__ float lpart[8][8][32];       // 8 KB [jh][row][b]
    __shared__ float lout[2][NB][9];        // padded output stage
    __shared__ int   lcnt[4];

    const int wg = blockIdx.x;
    const int t  = threadIdx.x;
    const int i0 = wg * 8;
    const int cur = step & 1;

    // stage spike bits (8 KB), 8 B/thread, coalesced
    ((uint2*)lbits)[t] = ((const uint2*)(bitsG + (size_t)cur * NN))[t];

    // compute identity: 2 rows per thread
    const int rh = t >> 8;          // 0..3 -> rows 2rh, 2rh+1
    const int jh = (t >> 5) & 7;    // chunk 0..7
    const int b  = t & 31;          // batch

    // hoisted state loads for combine threads (consumed after the FMA loop)
    float mem = 0.0f, xv = 0.0f, biasv = 0.0f;
    if (t < 256) {
        const int cil = t >> 5, cb = t & 31;
        mem   = mem_ws[(size_t)(i0 + cil) * NB + cb];   // coalesced [i][b]
        xv    = xT[step * NB + cb];
        biasv = bias[i0 + cil];
    }

    const float4* __restrict__ wr0 = (const float4*)(W + (size_t)(i0 + 2 * rh    ) * NN) + jh * 64;
    const float4* __restrict__ wr1 = (const float4*)(W + (size_t)(i0 + 2 * rh + 1) * NN) + jh * 64;

    __syncthreads();

    // chunk partial: 2 rows x 1 batch over 256 consecutive j, sequential order
    float c0 = 0.0f, c1 = 0.0f;
    const uint4* bp = ((const uint4*)lbits) + jh * 64;
    #pragma unroll 4
    for (int jj = 0; jj < 64; ++jj) {
        const float4 w0 = wr0[jj];
        const float4 w1 = wr1[jj];
        const uint4  bu = bp[jj];
        float s;
        s = (float)((bu.x >> b) & 1u); c0 = fmaf(w0.x, s, c0); c1 = fmaf(w1.x, s, c1);
        s = (float)((bu.y >> b) & 1u); c0 = fmaf(w0.y, s, c0); c1 = fmaf(w1.y, s, c1);
        s = (float)((bu.z >> b) & 1u); c0 = fmaf(w0.z, s, c0); c1 = fmaf(w1.z, s, c1);
        s = (float)((bu.w >> b) & 1u); c0 = fmaf(w0.w, s, c0); c1 = fmaf(w1.w, s, c1);
    }
    lpart[jh][2 * rh    ][b] = c0;
    lpart[jh][2 * rh + 1][b] = c1;
    __syncthreads();

    if (t < 256) {
        const int cil = t >> 5;     // row 0..7
        const int cb  = t & 31;     // batch

        // sequential combine over chunks (bit-exact R3/R5 order)
        float d = lpart[0][cil][cb];
        #pragma unroll
        for (int k = 1; k < 8; ++k) d += lpart[k][cil][cb];

        // prev spike from the staged bit (== stored ns exactly)
        float sp = (float)((lbits[i0 + cil] >> cb) & 1u);

        float base = 0.95f * mem + xv + d + biasv;
        float nm   = base * (1.0f - sp);
        float ns   = (nm > 1.0f) ? 1.0f : 0.0f;

        mem_ws[(size_t)(i0 + cil) * NB + cb] = nm;

        // publish spike bits for next step
        unsigned long long bal = __ballot(ns > 0.5f);
        unsigned int* bw = bitsG + (size_t)(1 - cur) * NN;
        const int l  = t & 63;
        const int w2 = t >> 6;
        if (l == 0)  bw[i0 + 2 * w2]     = (unsigned int)(bal & 0xFFFFFFFFull);
        if (l == 32) bw[i0 + 2 * w2 + 1] = (unsigned int)(bal >> 32);
        if (l == 0)  lcnt[w2] = __popcll(bal);

        lout[0][cb][cil] = ns;
        lout[1][cb][cil] = nm;
    }
    __syncthreads();

    if (t == 0) wgcnt[wg] += lcnt[0] + lcnt[1] + lcnt[2] + lcnt[3];

    // record stores (8 consecutive floats per (step,b))
    if (t < 512) {
        float* spk_rec = out + 1;
        float* mem_rec = out + 1 + (size_t)NT * NB * NN;
        const int arr = t >> 8;
        const int r2  = t & 255;
        const int bb  = r2 >> 3;
        const int il  = r2 & 7;
        size_t o = ((size_t)step * NB + bb) * (size_t)NN + i0 + il;
        if (arr == 0) __builtin_nontemporal_store(lout[0][bb][il], &spk_rec[o]);
        else          __builtin_nontemporal_store(lout[1][bb][il], &mem_rec[o]);
    }
}

__global__ void final_kernel(float* __restrict__ out, const int* __restrict__ wgcnt) {
    long long s = 0;
    for (int k = 0; k < NWG; ++k) s += wgcnt[k];
    out[0] = (float)((double)s / (double)((long long)NT * NB * NN));
}

extern "C" void kernel_launch(void* const* d_in, const int* in_sizes, int n_in,
                              void* d_out, int out_size, void* d_ws, size_t ws_size,
                              hipStream_t stream) {
    const float* x    = (const float*)d_in[0];  // (32, 500, 1)
    const float* W    = (const float*)d_in[1];  // (2048, 2048)
    const float* bias = (const float*)d_in[2];  // (2048,)
    float* out = (float*)d_out;

    unsigned int* bitsG  = (unsigned int*)d_ws;
    float*        mem_ws = (float*)((char*)d_ws + 16384);
    float*        xT     = (float*)((char*)d_ws + 278528);
    int*          wgcnt  = (int*)((char*)d_ws + 344064);

    init_kernel<<<dim3(256), dim3(256), 0, stream>>>(x, bitsG, mem_ws, xT, wgcnt);
    for (int step = 0; step < NT; ++step) {
        step_kernel<<<dim3(NWG), dim3(WGS), 0, stream>>>(W, bias, out, bitsG,
                                                         mem_ws, xT, wgcnt, step);
    }
    final_kernel<<<dim3(1), dim3(1), 0, stream>>>(out, wgcnt);
}